// Round 5
// baseline (346.057 us; speedup 1.0000x reference)
//
#include <hip/hip_runtime.h>
#include <hip/hip_bf16.h>
#include <stdint.h>

// Problem constants (fixed by the reference)
#define NROW 2048
#define HDIM 1024
#define VOC  50304
#define KCL  16
#define CDIM 3144   // VOC / KCL

// Tail-GEMM tiling: 128x128 tile, BK=32, 16 MFMA/wave-iter
#define MT 128
#define NT 128
#define BK 32
#define PK 36         // B LDS stride (u16): 72 B -> 2-way bank spread (free)
#define NCT 25        // ceil(3144/128)
#define MAXTILES 32   // sum ceil(Mk/128): Mk~128+-35 -> <= 32 safely

// Workspace layout in 4-byte units
#define WS_SUMEXP 0            // float[2048] (zeroed each call)
#define WS_COUNTS 2048         // int[16]     (zeroed each call)
#define WS_PART   2064         // float[2048]
#define WS_ZTGT   4112         // float[2048]
#define WS_TCOL   6160         // int[2048]
#define WS_ROWS   8208         // int[16*2048]
#define WS_NTILE  40976        // int
#define WS_TILES  40977        // int[2*32]
#define WS_XB     65536        // bf16[2048][1024]

typedef unsigned short u16;
typedef __attribute__((ext_vector_type(8))) short short8;
typedef __attribute__((ext_vector_type(4))) short short4v;
typedef __attribute__((ext_vector_type(4))) float f32x4;
typedef __attribute__((ext_vector_type(4))) unsigned short ushort4v;

__device__ __forceinline__ ushort2 f2bf2(float a, float b) {
    union { __hip_bfloat162 h; ushort2 u; } cv;
    cv.h = __float22bfloat162_rn(float2{a, b});
    return cv.u;
}

// async global->LDS, 16B/lane; LDS dest = wave-uniform base + lane*16
__device__ __forceinline__ void gload16(const void* g, void* lds) {
    __builtin_amdgcn_global_load_lds(
        (__attribute__((address_space(1))) void*)(g),
        (__attribute__((address_space(3))) void*)(lds), 16, 0, 0);
}

// ---------------------------------------------------------------------------
// Kernel 1: bucket rows by cluster, record target within-cluster column
// ---------------------------------------------------------------------------
__global__ void scatter_kernel(const int* __restrict__ y,
                               const int* __restrict__ y_pos,
                               const int* __restrict__ tip,
                               int* ws_i) {
    int n = blockIdx.x * 256 + threadIdx.x;
    if (n >= NROW) return;
    int kn = y_pos[n];
    int slot = atomicAdd(&ws_i[WS_COUNTS + kn], 1);
    ws_i[WS_ROWS + kn * NROW + slot] = n;
    ws_i[WS_TCOL + n] = tip[kn * VOC + y[n]];
}

// ---------------------------------------------------------------------------
// Kernel 1b: build compacted (cluster, row-tile) list — one wave, shfl scan
// ---------------------------------------------------------------------------
__global__ void plan_kernel(int* ws_i) {
    int lane = threadIdx.x;
    int nt = (lane < KCL) ? (ws_i[WS_COUNTS + lane] + MT - 1) / MT : 0;
    int pre = nt;
#pragma unroll
    for (int off = 1; off < 16; off <<= 1) {
        int v = __shfl_up(pre, off);
        if ((lane & 15) >= off) pre += v;
    }
    int start = pre - nt;
    if (lane < KCL) {
        for (int r = 0; r < nt; r++) {
            ws_i[WS_TILES + 2 * (start + r)]     = lane;
            ws_i[WS_TILES + 2 * (start + r) + 1] = r;
        }
        if (lane == KCL - 1) ws_i[WS_NTILE] = start + nt;
    }
}

// ---------------------------------------------------------------------------
// Kernel 2: cluster logsumexp part (fp32, tiny). One wave per row.
// ---------------------------------------------------------------------------
__global__ void cluster_kernel(const float* __restrict__ x,
                               const float* __restrict__ cw,
                               const int* __restrict__ y_pos,
                               float* ws_f) {
    int wave = threadIdx.x >> 6;
    int lane = threadIdx.x & 63;
    int n = blockIdx.x * 4 + wave;
    float acc[KCL];
#pragma unroll
    for (int k = 0; k < KCL; k++) acc[k] = 0.f;
#pragma unroll
    for (int j = 0; j < 16; j++) {
        int h = j * 64 + lane;
        float xv = x[(size_t)n * HDIM + h];
        const float4* cwr = (const float4*)(cw + (size_t)h * KCL);
#pragma unroll
        for (int q = 0; q < 4; q++) {
            float4 w = cwr[q];
            acc[q * 4 + 0] += xv * w.x;
            acc[q * 4 + 1] += xv * w.y;
            acc[q * 4 + 2] += xv * w.z;
            acc[q * 4 + 3] += xv * w.w;
        }
    }
#pragma unroll
    for (int off = 32; off >= 1; off >>= 1) {
#pragma unroll
        for (int k = 0; k < KCL; k++) acc[k] += __shfl_down(acc[k], off);
    }
    if (lane == 0) {
        int kn = y_pos[n];
        float m = acc[0];
#pragma unroll
        for (int k = 1; k < KCL; k++) m = fmaxf(m, acc[k]);
        float s = 0.f, skn = 0.f;
#pragma unroll
        for (int k = 0; k < KCL; k++) {
            s += __expf(acc[k] - m);
            skn = (k == kn) ? acc[k] : skn;
        }
        ws_f[WS_PART + n] = (m + __logf(s)) - skn;
    }
}

// ---------------------------------------------------------------------------
// Kernel 3a: x fp32 [N][H] -> bf16 xb [N][H] (4 MB: fits per-XCD L2, so the
// tail's 25 re-reads of A come from L2 instead of HBM/L3)
// ---------------------------------------------------------------------------
__global__ void convx_kernel(const float* __restrict__ x, u16* __restrict__ xb) {
    int t = blockIdx.x * 256 + threadIdx.x;
    float4 f = ((const float4*)x)[t];
    ushort2 a = f2bf2(f.x, f.y);
    ushort2 b = f2bf2(f.z, f.w);
    ushort4v v = {a.x, a.y, b.x, b.y};
    *(ushort4v*)(xb + (size_t)t * 4) = v;
}

// ---------------------------------------------------------------------------
// Kernel 4: tail GEMM. 128x128 tile (min logits traffic: each cluster is
// ~1 row-tile, so logits streams ~1.1x). A: async global_load_lds from bf16
// xb. B: register-pipelined fp32 loads + in-loop cvt (next iter's loads
// drain under the 16-MFMA phase).
// ---------------------------------------------------------------------------
__launch_bounds__(256)
__global__ void tail_kernel(const u16* __restrict__ xb,
                            const float* __restrict__ logits,
                            const int* ws_i, float* ws_f) {
    __shared__ __align__(16) u16 As[MT * BK];   // 8 KB [row][32] unpadded
    __shared__ __align__(16) u16 Bs[NT * PK];   // 9 KB [col][36]
    __shared__ int   lrow[MT];
    __shared__ int   ltcol[MT];
    __shared__ float rowsum[MT];

    const int ntile = ws_i[WS_NTILE];
    if ((int)blockIdx.y >= ntile) return;
    const int kcl = ws_i[WS_TILES + 2 * blockIdx.y];
    const int rt  = ws_i[WS_TILES + 2 * blockIdx.y + 1];
    const int ct  = blockIdx.x;
    const int Mk  = ws_i[WS_COUNTS + kcl];

    const int tid = threadIdx.x;
    if (tid < MT) {
        int r = rt * MT + tid;
        int rid = (r < Mk) ? ws_i[WS_ROWS + kcl * NROW + r] : -1;
        lrow[tid]  = rid;
        ltcol[tid] = (rid >= 0) ? ws_i[WS_TCOL + rid] : -1;
        rowsum[tid] = 0.f;
    }
    __syncthreads();

    const int w    = tid >> 6;
    const int l    = tid & 63;
    const int quad = l >> 4;
    const int lm   = l & 15;

    // --- A staging: wave w covers rows [32w, 32w+32) in 2 instrs ---
    int ar0 = w * 32 + (l >> 2);
    int ar1 = ar0 + 16;
    int rid0 = lrow[ar0]; if (rid0 < 0) rid0 = 0;   // masked in epilogue
    int rid1 = lrow[ar1]; if (rid1 < 0) rid1 = 0;
    const u16* agp0 = xb + (size_t)rid0 * HDIM + (l & 3) * 8;
    const u16* agp1 = xb + (size_t)rid1 * HDIM + (l & 3) * 8;
    char* alds0 = (char*)As + w * 2048;
    char* alds1 = (char*)As + w * 2048 + 1024;

    // --- B staging: thread t -> col t&127, k-half (t>>7)*16 ---
    const int bc  = tid & 127;
    const int bk0 = (tid >> 7) * 16;
    int gc = ct * NT + bc; if (gc >= CDIM) gc = CDIM - 1;   // clamp last tile
    const float* bp = logits + (size_t)(kcl * CDIM + gc) + (size_t)bk0 * VOC;

    float br[16];
#pragma unroll
    for (int k = 0; k < 16; k++) br[k] = bp[(size_t)k * VOC];
    bp += (size_t)BK * VOC;

    f32x4 acc[4][4];
#pragma unroll
    for (int mi = 0; mi < 4; mi++)
#pragma unroll
        for (int ni = 0; ni < 4; ni++) acc[mi][ni] = (f32x4)(0.f);

    const int wr = (w >> 1) * 64;
    const int wc = (w & 1) * 64;
    union fr { short4v h[2]; short8 s; };

    for (int h0 = 0; h0 < HDIM; h0 += BK) {
        // A async global->LDS (this iter)
        gload16(agp0, alds0);
        gload16(agp1, alds1);
        agp0 += BK; agp1 += BK;
        // B cvt staged regs -> LDS (this iter)
#pragma unroll
        for (int j = 0; j < 4; j++) {
            ushort2 p0 = f2bf2(br[j * 4 + 0], br[j * 4 + 1]);
            ushort2 p1 = f2bf2(br[j * 4 + 2], br[j * 4 + 3]);
            ushort4v v = {p0.x, p0.y, p1.x, p1.y};
            *(ushort4v*)&Bs[bc * PK + bk0 + j * 4] = v;
        }
        __syncthreads();   // drains A vmcnt + B lgkm -> tiles valid

        // issue next iter's B loads; drain under MFMA phase
        if (h0 + BK < HDIM) {
#pragma unroll
            for (int k = 0; k < 16; k++) br[k] = bp[(size_t)k * VOC];
            bp += (size_t)BK * VOC;
        }

        // fragments + MFMA
        short8 a[4], b[4];
#pragma unroll
        for (int mi = 0; mi < 4; mi++)
            a[mi] = *(const short8*)&As[(wr + mi * 16 + lm) * BK + quad * 8];
#pragma unroll
        for (int ni = 0; ni < 4; ni++) {
            fr f;
            const short4v* p = (const short4v*)&Bs[(wc + ni * 16 + lm) * PK + quad * 8];
            f.h[0] = p[0]; f.h[1] = p[1];
            b[ni] = f.s;
        }
#pragma unroll
        for (int mi = 0; mi < 4; mi++)
#pragma unroll
            for (int ni = 0; ni < 4; ni++)
                acc[mi][ni] = __builtin_amdgcn_mfma_f32_16x16x32_bf16(
                    a[mi], b[ni], acc[mi][ni], 0, 0, 0);
        __syncthreads();
    }

    // epilogue: C/D layout col=lane&15, row=(lane>>4)*4+reg [m89-verified]
#pragma unroll
    for (int mi = 0; mi < 4; mi++) {
#pragma unroll
        for (int r = 0; r < 4; r++) {
            int row_local = wr + mi * 16 + quad * 4 + r;
            int rid = lrow[row_local];
            int tc  = ltcol[row_local];
            float s = 0.f;
#pragma unroll
            for (int ni = 0; ni < 4; ni++) {
                int cl = ct * NT + wc + ni * 16 + lm;
                float z = acc[mi][ni][r];
                if (rid >= 0 && cl < CDIM) {
                    s += __expf(z);
                    if (cl == tc) ws_f[WS_ZTGT + rid] = z;
                }
            }
            s += __shfl_xor(s, 1);
            s += __shfl_xor(s, 2);
            s += __shfl_xor(s, 4);
            s += __shfl_xor(s, 8);
            if (lm == 0 && rid >= 0) atomicAdd(&rowsum[row_local], s);
        }
    }
    __syncthreads();
    if (tid < MT) {
        int rid = lrow[tid];
        if (rid >= 0) atomicAdd(&ws_f[WS_SUMEXP + rid], rowsum[tid]);
    }
}

// ---------------------------------------------------------------------------
// Kernel 5: nll[n] = part[n] + log(sumexp[n]) - z_target[n]
// ---------------------------------------------------------------------------
__global__ void finalize_kernel(const float* ws_f, float* __restrict__ out) {
    int n = blockIdx.x * 256 + threadIdx.x;
    if (n >= NROW) return;
    out[n] = ws_f[WS_PART + n] + __logf(ws_f[WS_SUMEXP + n]) - ws_f[WS_ZTGT + n];
}

// ---------------------------------------------------------------------------
extern "C" void kernel_launch(void* const* d_in, const int* in_sizes, int n_in,
                              void* d_out, int out_size, void* d_ws, size_t ws_size,
                              hipStream_t stream) {
    const float* x      = (const float*)d_in[0];
    const int*   y      = (const int*)d_in[1];
    const int*   y_pos  = (const int*)d_in[2];
    // d_in[3] (pos2token) is the identity partition; unused.
    const int*   tip    = (const int*)d_in[4];
    const float* cw     = (const float*)d_in[5];
    const float* logits = (const float*)d_in[6];
    float* out  = (float*)d_out;
    float* ws_f = (float*)d_ws;
    int*   ws_i = (int*)d_ws;
    u16*   xb   = (u16*)((float*)d_ws + WS_XB);

    hipMemsetAsync(d_ws, 0, (size_t)(NROW + KCL) * 4, stream);

    scatter_kernel<<<NROW / 256, 256, 0, stream>>>(y, y_pos, tip, ws_i);
    plan_kernel<<<1, 64, 0, stream>>>(ws_i);
    cluster_kernel<<<NROW / 4, 256, 0, stream>>>(x, cw, y_pos, ws_f);
    convx_kernel<<<NROW * HDIM / 4 / 256, 256, 0, stream>>>(x, xb);

    dim3 grid(NCT, MAXTILES);   // 25 x 32
    tail_kernel<<<grid, 256, 0, stream>>>(xb, logits, ws_i, ws_f);

    finalize_kernel<<<NROW / 256, 256, 0, stream>>>(ws_f, out);
}